// Round 3
// baseline (358.711 us; speedup 1.0000x reference)
//
#include <hip/hip_runtime.h>
#include <math.h>

// ============================================================================
// Attention block (B=8, C=512, H=W=32, nh=8, hd=64) via bf16x3 MFMA.
// Round 3: attention rebuilt — 512-thread blocks (2 waves/SIMD), double-
// buffered K/V in LDS with ONE barrier/iter, Q/K stored as hi/lo bf16 planes
// (no unpack), V as single bf16 plane (PV = 1 MFMA), stride-68 LDS (2-way
// bank aliasing = free).  GEMM cores unchanged from round 2.
// ============================================================================

typedef unsigned int u32;
typedef float  f32x4 __attribute__((ext_vector_type(4)));
typedef short  s16x8 __attribute__((ext_vector_type(8)));
typedef unsigned short u16x4 __attribute__((ext_vector_type(4)));
typedef unsigned int   u32x4 __attribute__((ext_vector_type(4)));

#define MFMA16(a, b, c) __builtin_amdgcn_mfma_f32_16x16x32_bf16(a, b, c, 0, 0, 0)

// split fp32 -> (hi bf16 << 16) | lo bf16.  hi = truncation, lo = RNE(f - hi)
__device__ __forceinline__ u32 splitpack(float f) {
    u32 b = __float_as_uint(f);
    u32 hb = b & 0xFFFF0000u;
    float lf = f - __uint_as_float(hb);
    u32 lb = __float_as_uint(lf);
    u32 lr = (lb + 0x7FFFu + ((lb >> 16) & 1u)) >> 16;
    return hb | (lr & 0xFFFFu);
}
__device__ __forceinline__ ushort f2bf(float f) {  // RNE fp32->bf16
    u32 b = __float_as_uint(f);
    return (ushort)((b + 0x7FFFu + ((b >> 16) & 1u)) >> 16);
}
__device__ __forceinline__ void unpack4(u32x4 v, u16x4& hi, u16x4& lo) {
    hi[0] = (ushort)(v.x >> 16); hi[1] = (ushort)(v.y >> 16);
    hi[2] = (ushort)(v.z >> 16); hi[3] = (ushort)(v.w >> 16);
    lo[0] = (ushort)v.x; lo[1] = (ushort)v.y;
    lo[2] = (ushort)v.z; lo[3] = (ushort)v.w;
}

// ---------------------------------------------------------------------------
// split_w: both weight matrices -> hi/lo bf16 planes, same [o][c] layout.
// ---------------------------------------------------------------------------
__global__ __launch_bounds__(256) void split_w(const float* __restrict__ wq,
                                               const float* __restrict__ wp,
                                               ushort* __restrict__ wq_h, ushort* __restrict__ wq_l,
                                               ushort* __restrict__ wp_h, ushort* __restrict__ wp_l) {
    size_t base = ((size_t)blockIdx.x * 256 + threadIdx.x) * 4;
    const float* src; ushort *dh, *dl; size_t off;
    if (base < 786432) { src = wq; dh = wq_h; dl = wq_l; off = base; }
    else               { src = wp; dh = wp_h; dl = wp_l; off = base - 786432; }
    f32x4 v = *(const f32x4*)(src + off);
    u16x4 hi, lo;
#pragma unroll
    for (int e = 0; e < 4; e++) { u32 pk = splitpack(v[e]); hi[e] = (ushort)(pk >> 16); lo[e] = (ushort)pk; }
    *(u16x4*)(dh + off) = hi;
    *(u16x4*)(dl + off) = lo;
}

// ---------------------------------------------------------------------------
// split_x: x[b][c][n] fp32 -> xt hi/lo [bl][n][c] bf16 (64x64 tile transpose).
// ---------------------------------------------------------------------------
__global__ __launch_bounds__(256) void split_x(const float* __restrict__ x,
                                               ushort* __restrict__ xh, ushort* __restrict__ xl,
                                               int bbase) {
    __shared__ __align__(16) ushort Th[64 * 72];
    __shared__ __align__(16) ushort Tl[64 * 72];
    const int t = threadIdx.x;
    const int n0 = blockIdx.x * 64, c0 = blockIdx.y * 64, bz = blockIdx.z;
    const int b = bbase + bz;
    const int c = t >> 2, nseg = (t & 3) * 4;
    const float* src = x + ((size_t)b * 512 + c0 + c) * 1024 + n0;
#pragma unroll
    for (int i = 0; i < 4; i++) {
        f32x4 v = *(const f32x4*)(src + nseg + i * 16);
#pragma unroll
        for (int e = 0; e < 4; e++) {
            u32 pk = splitpack(v[e]);
            int nl = nseg + i * 16 + e;
            Th[nl * 72 + c] = (ushort)(pk >> 16);
            Tl[nl * 72 + c] = (ushort)pk;
        }
    }
    __syncthreads();
#pragma unroll
    for (int i = 0; i < 2; i++) {
        int nl = i * 32 + (t >> 3);
        int u = t & 7;
        s16x8 vh = *(const s16x8*)(Th + nl * 72 + u * 8);
        s16x8 vl = *(const s16x8*)(Tl + nl * 72 + u * 8);
        size_t go = ((size_t)bz * 1024 + n0 + nl) * 512 + c0 + u * 8;
        *(s16x8*)(xh + go) = vh;
        *(s16x8*)(xl + go) = vl;
    }
}

// ---------------------------------------------------------------------------
// Shared bf16x3 GEMM mainloop: 128x128 tile, BK=32, reg-prefetched staging.
// acc[Mt][Nt]: D rows o = ohalf*64+Mt*16+quad*4+r, cols n = nhalf*64+Nt*16+l15.
// ---------------------------------------------------------------------------
__device__ __forceinline__ void gemm_core(
    const ushort* __restrict__ Ah_g, const ushort* __restrict__ Al_g, int arow0,
    const ushort* __restrict__ Bh_g, const ushort* __restrict__ Bl_g, size_t brow0,
    ushort* smem, f32x4 (&acc)[4][4]) {
    const int t = threadIdx.x;
    ushort* As_h = smem;
    ushort* As_l = smem + 5120;
    ushort* Bs_h = smem + 10240;
    ushort* Bs_l = smem + 15360;
    const int ro = t >> 1, cs = (t & 1) << 4;
    const size_t ga = (size_t)(arow0 + ro) * 512 + cs;
    const size_t gb = (brow0 + ro) * 512 + cs;
    const int l15 = t & 15, quad = (t >> 4) & 3, wv = t >> 6;
    const int lra = (((wv >> 1) * 64) + l15) * 40 + quad * 8;
    const int lrb = (((wv & 1) * 64) + l15) * 40 + quad * 8;
    const int lw = ro * 40 + cs;

    s16x8 vah0 = *(const s16x8*)(Ah_g + ga),     vah1 = *(const s16x8*)(Ah_g + ga + 8);
    s16x8 val0 = *(const s16x8*)(Al_g + ga),     val1 = *(const s16x8*)(Al_g + ga + 8);
    s16x8 vbh0 = *(const s16x8*)(Bh_g + gb),     vbh1 = *(const s16x8*)(Bh_g + gb + 8);
    s16x8 vbl0 = *(const s16x8*)(Bl_g + gb),     vbl1 = *(const s16x8*)(Bl_g + gb + 8);

    for (int k0 = 0; k0 < 512; k0 += 32) {
        __syncthreads();
        *(s16x8*)(As_h + lw) = vah0; *(s16x8*)(As_h + lw + 8) = vah1;
        *(s16x8*)(As_l + lw) = val0; *(s16x8*)(As_l + lw + 8) = val1;
        *(s16x8*)(Bs_h + lw) = vbh0; *(s16x8*)(Bs_h + lw + 8) = vbh1;
        *(s16x8*)(Bs_l + lw) = vbl0; *(s16x8*)(Bs_l + lw + 8) = vbl1;
        const int kn = (k0 + 32) & 511;  // wraps to 0 on last iter (discarded)
        vah0 = *(const s16x8*)(Ah_g + ga + kn); vah1 = *(const s16x8*)(Ah_g + ga + kn + 8);
        val0 = *(const s16x8*)(Al_g + ga + kn); val1 = *(const s16x8*)(Al_g + ga + kn + 8);
        vbh0 = *(const s16x8*)(Bh_g + gb + kn); vbh1 = *(const s16x8*)(Bh_g + gb + kn + 8);
        vbl0 = *(const s16x8*)(Bl_g + gb + kn); vbl1 = *(const s16x8*)(Bl_g + gb + kn + 8);
        __syncthreads();
        s16x8 ah[4], al[4], bh[4], bl[4];
#pragma unroll
        for (int Mt = 0; Mt < 4; Mt++) {
            ah[Mt] = *(const s16x8*)(As_h + lra + Mt * 640);
            al[Mt] = *(const s16x8*)(As_l + lra + Mt * 640);
        }
#pragma unroll
        for (int Nt = 0; Nt < 4; Nt++) {
            bh[Nt] = *(const s16x8*)(Bs_h + lrb + Nt * 640);
            bl[Nt] = *(const s16x8*)(Bs_l + lrb + Nt * 640);
        }
#pragma unroll
        for (int Mt = 0; Mt < 4; Mt++)
#pragma unroll
            for (int Nt = 0; Nt < 4; Nt++) {
                acc[Mt][Nt] = MFMA16(ah[Mt], bh[Nt], acc[Mt][Nt]);
                acc[Mt][Nt] = MFMA16(ah[Mt], bl[Nt], acc[Mt][Nt]);
                acc[Mt][Nt] = MFMA16(al[Mt], bh[Nt], acc[Mt][Nt]);
            }
    }
    __syncthreads();  // LDS free for epilogue reuse
}

// ---------------------------------------------------------------------------
// QKV GEMM. o-halves (64 rows) align exactly to q/k/v roles: g = ot*2+ohalf,
// role = g%3 (0=q,1=k,2=v), head = g/3.  Q/K -> LDS transpose -> hi/lo bf16
// planes [b][h][n][d]; V -> single bf16 plane [b][h][d][n].
// ---------------------------------------------------------------------------
__global__ __launch_bounds__(256) void gemm_qkv(
    const ushort* __restrict__ wq_h, const ushort* __restrict__ wq_l,
    const ushort* __restrict__ xt_h, const ushort* __restrict__ xt_l,
    ushort* __restrict__ qhT, ushort* __restrict__ qlT,
    ushort* __restrict__ khT, ushort* __restrict__ klT,
    ushort* __restrict__ vbT) {
    __shared__ __align__(16) ushort smem[20480];
    f32x4 acc[4][4];
#pragma unroll
    for (int i = 0; i < 4; i++)
#pragma unroll
        for (int j = 0; j < 4; j++) acc[i][j] = (f32x4)0.0f;

    const int n0 = blockIdx.x * 128, o0 = blockIdx.y * 128, bz = blockIdx.z;
    gemm_core(wq_h, wq_l, o0, xt_h, xt_l, (size_t)bz * 1024 + n0, smem, acc);

    const int t = threadIdx.x;
    const int l15 = t & 15, quad = (t >> 4) & 3, wv = t >> 6, lane = t & 63;
    const int g = blockIdx.y * 2 + (wv >> 1);
    const int role = g % 3, head = g / 3;
    const int nh = (wv & 1) * 64;
    const size_t hb = (size_t)bz * 8 + head;
    const float scale = (role == 0) ? 0.125f : 1.0f;

    if (role < 2) {
        ushort* dh = (role == 0) ? qhT : khT;
        ushort* dl = (role == 0) ? qlT : klT;
        u32* T = (u32*)smem + wv * 2304;             // per-wave [64 n][36] u32
        const size_t rowbase = hb * 1024 + n0 + nh;  // pixel row index
#pragma unroll
        for (int sp = 0; sp < 2; sp++) {
#pragma unroll
            for (int Mti = 0; Mti < 2; Mti++)
#pragma unroll
                for (int Nt = 0; Nt < 4; Nt++) {
                    f32x4 v = acc[sp * 2 + Mti][Nt];
                    u32x4 pix;
#pragma unroll
                    for (int r = 0; r < 4; r++) pix[r] = splitpack(v[r] * scale);
                    *(u32x4*)(T + (Nt * 16 + l15) * 36 + Mti * 16 + quad * 4) = pix;
                }
            asm volatile("s_waitcnt lgkmcnt(0)" ::: "memory");
#pragma unroll
            for (int i = 0; i < 8; i++) {
                int nl = i * 8 + (lane >> 3);
                u32x4 vv = *(const u32x4*)(T + nl * 36 + (lane & 7) * 4);
                u16x4 hi, lo; unpack4(vv, hi, lo);
                size_t go = (rowbase + nl) * 64 + sp * 32 + (lane & 7) * 4;
                *(u16x4*)(dh + go) = hi;
                *(u16x4*)(dl + go) = lo;
            }
            asm volatile("s_waitcnt lgkmcnt(0)" ::: "memory");
        }
    } else {
        const size_t vb2 = hb * 64 * 1024 + (size_t)(n0 + nh);
#pragma unroll
        for (int Mt = 0; Mt < 4; Mt++)
#pragma unroll
            for (int Nt = 0; Nt < 4; Nt++)
#pragma unroll
                for (int r = 0; r < 4; r++)
                    vbT[vb2 + (size_t)(Mt * 16 + quad * 4 + r) * 1024 + Nt * 16 + l15] =
                        f2bf(acc[Mt][Nt][r]);
    }
}

// ---------------------------------------------------------------------------
// Proj GEMM: out fp32 + bias, direct C/D stores.
// ---------------------------------------------------------------------------
__global__ __launch_bounds__(256) void gemm_proj(
    const ushort* __restrict__ wp_h, const ushort* __restrict__ wp_l,
    const ushort* __restrict__ ht_h, const ushort* __restrict__ ht_l,
    const float* __restrict__ bias, float* __restrict__ out) {
    __shared__ __align__(16) ushort smem[20480];
    f32x4 acc[4][4];
#pragma unroll
    for (int i = 0; i < 4; i++)
#pragma unroll
        for (int j = 0; j < 4; j++) acc[i][j] = (f32x4)0.0f;

    const int n0 = blockIdx.x * 128, o0 = blockIdx.y * 128, bz = blockIdx.z;
    gemm_core(wp_h, wp_l, o0, ht_h, ht_l, (size_t)bz * 1024 + n0, smem, acc);

    const int t = threadIdx.x;
    const int l15 = t & 15, quad = (t >> 4) & 3, wv = t >> 6;
#pragma unroll
    for (int Mt = 0; Mt < 4; Mt++)
#pragma unroll
        for (int Nt = 0; Nt < 4; Nt++) {
            int ob = o0 + (wv >> 1) * 64 + Mt * 16 + quad * 4;
            int nn = n0 + (wv & 1) * 64 + Nt * 16 + l15;
#pragma unroll
            for (int r = 0; r < 4; r++)
                out[((size_t)bz * 512 + ob + r) * 1024 + nn] = acc[Mt][Nt][r] + bias[ob + r];
        }
}

// ---------------------------------------------------------------------------
// Flash attention, round 3.  512 threads (8 waves, 2/SIMD), one (b,h) + 128
// queries per block, 16 key tiles of 64.  K hi/lo + V bf16 double-buffered in
// LDS; ONE barrier per iter (Ps is per-wave-private).  All LDS strides 68
// ushort = 34 dwords == 2 mod 32 -> 2-way bank aliasing (free).
// LDS map (ushort idx): Kh[2]@0/4352, Kl[2]@8704/13056, Vb[2]@17408/21760,
// Ps[128][68]@26112.  Total 34816 ushort = 69,632 B.
// ---------------------------------------------------------------------------
__global__ __launch_bounds__(512) void attn_mfma(
    const ushort* __restrict__ qhT, const ushort* __restrict__ qlT,
    const ushort* __restrict__ khT, const ushort* __restrict__ klT,
    const ushort* __restrict__ vbT,
    ushort* __restrict__ ht_h, ushort* __restrict__ ht_l, int bbase) {
    __shared__ __align__(16) ushort sm[34816];
    const int t = threadIdx.x;
    const int qt = blockIdx.x, bh = blockIdx.y;
    const int bl = bh >> 3, h = bh & 7;
    const int m0 = qt * 128;
    const size_t hb = (size_t)bl * 8 + h;
    const int l15 = t & 15, quad = (t >> 4) & 3, wv = t >> 6;
    const int row = t >> 3, seg = t & 7;
    ushort* Ps = sm + 26112;

    // Persistent Q fragments (pre-scaled by 0.125); wave owns m = wv*16+l15
    s16x8 qfh[2], qfl[2];
    {
        const size_t qb = (hb * 1024 + m0 + wv * 16 + l15) * 64 + quad * 8;
        qfh[0] = *(const s16x8*)(qhT + qb);
        qfh[1] = *(const s16x8*)(qhT + qb + 32);
        qfl[0] = *(const s16x8*)(qlT + qb);
        qfl[1] = *(const s16x8*)(qlT + qb + 32);
    }

    const size_t kgb = (hb * 1024 + row) * 64 + seg * 8;  // + kt*4096
    const size_t vgb = (hb * 64 + row) * 1024 + seg * 8;  // + kt*64
    const int lw = row * 68 + seg * 8;

    // Prologue: stage kt=0 into buffer 0
    {
        s16x8 k0h = *(const s16x8*)(khT + kgb);
        s16x8 k0l = *(const s16x8*)(klT + kgb);
        s16x8 v0  = *(const s16x8*)(vbT + vgb);
        *(s16x8*)(sm + lw) = k0h;
        *(s16x8*)(sm + 8704 + lw) = k0l;
        *(s16x8*)(sm + 17408 + lw) = v0;
    }
    f32x4 O[4];
#pragma unroll
    for (int i = 0; i < 4; i++) O[i] = (f32x4)0.0f;
    float mrun = -3.0e38f, lrun = 0.f;
    __syncthreads();

    for (int kt = 0; kt < 16; kt++) {
        const int cur = kt & 1, nxt = cur ^ 1;
        const int ktn = (kt + 1) & 15;  // wraps; last-iter prefetch discarded
        // Prefetch next K/V tile into regs (overlaps all compute below)
        s16x8 rkh = *(const s16x8*)(khT + kgb + (size_t)ktn * 4096);
        s16x8 rkl = *(const s16x8*)(klT + kgb + (size_t)ktn * 4096);
        s16x8 rv  = *(const s16x8*)(vbT + vgb + ktn * 64);

        const ushort* Khc = sm + cur * 4352;
        const ushort* Klc = sm + 8704 + cur * 4352;
        const ushort* Vbc = sm + 17408 + cur * 4352;

        // S = K^T Q  (D: row nk = Mt*16+quad*4+r, col m = wv*16+l15)
        f32x4 S[4];
#pragma unroll
        for (int i = 0; i < 4; i++) S[i] = (f32x4)0.0f;
#pragma unroll
        for (int ks = 0; ks < 2; ks++) {
            s16x8 kh[4], kl[4];
#pragma unroll
            for (int Mt = 0; Mt < 4; Mt++) {
                kh[Mt] = *(const s16x8*)(Khc + (Mt * 16 + l15) * 68 + ks * 32 + quad * 8);
                kl[Mt] = *(const s16x8*)(Klc + (Mt * 16 + l15) * 68 + ks * 32 + quad * 8);
            }
#pragma unroll
            for (int Mt = 0; Mt < 4; Mt++) {
                S[Mt] = MFMA16(kh[Mt], qfh[ks], S[Mt]);
                S[Mt] = MFMA16(kh[Mt], qfl[ks], S[Mt]);
                S[Mt] = MFMA16(kl[Mt], qfh[ks], S[Mt]);
            }
        }
        // Online softmax over nk for this lane's column m
        float tm = -3.0e38f;
#pragma unroll
        for (int Mt = 0; Mt < 4; Mt++)
#pragma unroll
            for (int r = 0; r < 4; r++) tm = fmaxf(tm, S[Mt][r]);
        tm = fmaxf(tm, __shfl_xor(tm, 16));
        tm = fmaxf(tm, __shfl_xor(tm, 32));
        const float mnew = fmaxf(mrun, tm);
        const float alpha = __expf(mrun - mnew);
        float ts = 0.f;
#pragma unroll
        for (int Mt = 0; Mt < 4; Mt++)
#pragma unroll
            for (int r = 0; r < 4; r++) {
                float p = __expf(S[Mt][r] - mnew);
                S[Mt][r] = p;
                ts += p;
            }
        ts += __shfl_xor(ts, 16);
        ts += __shfl_xor(ts, 32);
        lrun = lrun * alpha + ts;
        mrun = mnew;
        // Write P (bf16) to per-wave-private LDS rows [m][nk] — no barrier
#pragma unroll
        for (int Mt = 0; Mt < 4; Mt++) {
            u16x4 pb;
#pragma unroll
            for (int r = 0; r < 4; r++) pb[r] = f2bf(S[Mt][r]);
            *(u16x4*)(Ps + (wv * 16 + l15) * 68 + Mt * 16 + quad * 4) = pb;
        }
        // O = O*alpha + V @ P
#pragma unroll
        for (int Mt = 0; Mt < 4; Mt++) O[Mt] *= alpha;
#pragma unroll
        for (int ks = 0; ks < 2; ks++) {
            s16x8 vf[4];
#pragma unroll
            for (int Mt = 0; Mt < 4; Mt++)
                vf[Mt] = *(const s16x8*)(Vbc + (Mt * 16 + l15) * 68 + ks * 32 + quad * 8);
            s16x8 pf = *(const s16x8*)(Ps + (wv * 16 + l15) * 68 + ks * 32 + quad * 8);
#pragma unroll
            for (int Mt = 0; Mt < 4; Mt++) O[Mt] = MFMA16(vf[Mt], pf, O[Mt]);
        }
        // Stage next tile into the other buffer, then the single barrier
        *(s16x8*)(sm + nxt * 4352 + lw) = rkh;
        *(s16x8*)(sm + 8704 + nxt * 4352 + lw) = rkl;
        *(s16x8*)(sm + 17408 + nxt * 4352 + lw) = rv;
        __syncthreads();
    }

    // Epilogue: O /= l, split hi/lo, LDS gather -> coalesced hT stores
    ushort* OLh = sm;          // [128][72]
    ushort* OLl = sm + 9216;
    const float linv = 1.f / lrun;
#pragma unroll
    for (int Mt = 0; Mt < 4; Mt++) {
        u16x4 hi, lo;
#pragma unroll
        for (int r = 0; r < 4; r++) {
            u32 pk = splitpack(O[Mt][r] * linv);
            hi[r] = (ushort)(pk >> 16);
            lo[r] = (ushort)pk;
        }
        const int m = wv * 16 + l15;
        *(u16x4*)(OLh + m * 72 + Mt * 16 + quad * 4) = hi;
        *(u16x4*)(OLl + m * 72 + Mt * 16 + quad * 4) = lo;
    }
    __syncthreads();
    const size_t ob = (size_t)(bbase + bl) * 1024 + m0;
#pragma unroll
    for (int i = 0; i < 2; i++) {
        const int m = i * 64 + (t >> 3);
        const int u = t & 7;
        s16x8 vh2 = *(const s16x8*)(OLh + m * 72 + u * 8);
        s16x8 vl2 = *(const s16x8*)(OLl + m * 72 + u * 8);
        size_t go = (ob + m) * 512 + h * 64 + u * 8;
        *(s16x8*)(ht_h + go) = vh2;
        *(s16x8*)(ht_l + go) = vl2;
    }
}

// ---------------------------------------------------------------------------
extern "C" void kernel_launch(void* const* d_in, const int* in_sizes, int n_in,
                              void* d_out, int out_size, void* d_ws, size_t ws_size,
                              hipStream_t stream) {
    (void)in_sizes; (void)n_in; (void)out_size; (void)ws_size;
    const float* x      = (const float*)d_in[0];
    const float* w_qkv  = (const float*)d_in[1];
    const float* w_proj = (const float*)d_in[2];
    const float* b_proj = (const float*)d_in[3];
    float* out = (float*)d_out;

    // workspace layout (bytes), total 50,331,648 (< 67 MB proven safe)
    char* ws = (char*)d_ws;
    ushort* xt_h = (ushort*)(ws);                       // 4,194,304
    ushort* xt_l = (ushort*)(ws + 4194304);             // 4,194,304
    ushort* wq_h = (ushort*)(ws + 8388608);             // 1,572,864
    ushort* wq_l = (ushort*)(ws + 9961472);             // 1,572,864
    ushort* wp_h = (ushort*)(ws + 11534336);            //   524,288
    ushort* wp_l = (ushort*)(ws + 12058624);            //   524,288
    ushort* qhT  = (ushort*)(ws + 12582912);            // 4,194,304
    ushort* qlT  = (ushort*)(ws + 16777216);            // 4,194,304
    ushort* khT  = (ushort*)(ws + 20971520);            // 4,194,304
    ushort* klT  = (ushort*)(ws + 25165824);            // 4,194,304
    ushort* vbT  = (ushort*)(ws + 29360128);            // 4,194,304
    ushort* ht_h = (ushort*)(ws + 33554432);            // 8,388,608
    ushort* ht_l = (ushort*)(ws + 41943040);            // 8,388,608

    split_w<<<1024, 256, 0, stream>>>(w_qkv, w_proj, wq_h, wq_l, wp_h, wp_l);
    for (int p = 0; p < 2; p++) {
        int bbase = p * 4;
        split_x<<<dim3(16, 8, 4), 256, 0, stream>>>(x, xt_h, xt_l, bbase);
        gemm_qkv<<<dim3(8, 12, 4), 256, 0, stream>>>(wq_h, wq_l, xt_h, xt_l,
                                                     qhT, qlT, khT, klT, vbT);
        attn_mfma<<<dim3(8, 32), 512, 0, stream>>>(qhT, qlT, khT, klT, vbT,
                                                   ht_h, ht_l, bbase);
    }
    gemm_proj<<<dim3(8, 4, 8), 256, 0, stream>>>(wp_h, wp_l, ht_h, ht_l, b_proj, out);
}